// Round 1
// baseline (213.127 us; speedup 1.0000x reference)
//
#include <hip/hip_runtime.h>

// Shapes (fixed by the problem)
#define BB 8
#define NN 64
#define DD 256
#define PP 256
#define NE 63      // N-1 edges per node
#define EE 4032    // N*(N-1) edges per batch

// dot[b*64+j] = node_features[b,j,:] . target[b,:]
__global__ __launch_bounds__(64) void k_dot(const float* __restrict__ nf,
                                            const float* __restrict__ tgt,
                                            float* __restrict__ dotv) {
    int row = blockIdx.x;          // b*NN + j
    int b = row >> 6;
    int lane = threadIdx.x;        // 0..63
    const float* x = nf + (size_t)row * DD;
    const float* t = tgt + (size_t)b * DD;
    float acc = 0.f;
#pragma unroll
    for (int i = 0; i < 4; ++i) acc += x[lane + 64 * i] * t[lane + 64 * i];
#pragma unroll
    for (int off = 32; off; off >>= 1) acc += __shfl_down(acc, off, 64);
    if (lane == 0) dotv[row] = acc;
}

// Per (b,n): s_e = dot[b, dst_e];  S = sum s_e
// conc[bn] = [ sum_e s_e*NF[src_e] | sum_e s_e*EF[e] | sum_e s_e*NF[dst_e] ]  (768 floats)
__global__ __launch_bounds__(256) void k_edge(const float* __restrict__ nf,
                                              const float* __restrict__ ef,
                                              const int* __restrict__ eidx,
                                              const float* __restrict__ dotv,
                                              float* __restrict__ conc,
                                              float* __restrict__ Svec) {
    __shared__ float s_sh[NE];
    __shared__ int src_sh[NE];
    __shared__ int dst_sh[NE];
    int bn = blockIdx.x;           // b*NN + n
    int b = bn >> 6, n = bn & 63;
    int t = threadIdx.x;           // 0..255 = feature dim
    if (t < NE) {
        const int* srcp = eidx + (size_t)b * 2 * EE + n * NE;
        int si = srcp[t];
        int di = srcp[EE + t];
        src_sh[t] = si;
        dst_sh[t] = di;
        s_sh[t] = dotv[(b << 6) + di];
    }
    __syncthreads();
    const float* efp = ef + ((size_t)b * EE + (size_t)n * NE) * DD + t;
    const float* nfb = nf + ((size_t)(b << 6)) * DD + t;
    float at = 0.f, aus = 0.f, aud = 0.f, S = 0.f;
#pragma unroll 7
    for (int e = 0; e < NE; ++e) {
        float sv = s_sh[e];
        S   += sv;
        at  += sv * efp[(size_t)e * DD];
        aus += sv * nfb[(size_t)src_sh[e] * DD];
        aud += sv * nfb[(size_t)dst_sh[e] * DD];
    }
    float* o = conc + (size_t)bn * 768;
    o[t]       = aus;
    o[256 + t] = at;
    o[512 + t] = aud;
    if (t == 0) Svec[bn] = S;
}

// 512 rows total; each block handles 2 rows, thread j = output column.
// retrieved = LN( ((conc@Wf0 + S*bf0)@Wf1 + S*bf1)@Wf2 + S*bf2 )
// out = ((([NF|retrieved|tgt])@Wi0 + bi0)@Wi1 + bi1)@Wi2 + bi2
__global__ __launch_bounds__(256) void k_mlp(const float* __restrict__ conc,
                                             const float* __restrict__ Svec,
                                             const float* __restrict__ nf,
                                             const float* __restrict__ tgt,
                                             const float* __restrict__ Wf0, const float* __restrict__ bf0,
                                             const float* __restrict__ Wf1, const float* __restrict__ bf1,
                                             const float* __restrict__ Wf2, const float* __restrict__ bf2,
                                             const float* __restrict__ gam, const float* __restrict__ bet,
                                             const float* __restrict__ Wi0, const float* __restrict__ bi0,
                                             const float* __restrict__ Wi1, const float* __restrict__ bi1,
                                             const float* __restrict__ Wi2, const float* __restrict__ bi2,
                                             float* __restrict__ outp) {
    __shared__ float A[1536];   // conc rows (2 x 768)
    __shared__ float Z[1536];   // final concat rows (2 x 768)
    __shared__ float H1[512];
    __shared__ float H2[512];
    __shared__ float red1[4], red2[4];
    int r0 = blockIdx.x * 2;
    int j = threadIdx.x;

#pragma unroll
    for (int i = 0; i < 6; ++i) A[j + 256 * i] = conc[(size_t)r0 * 768 + j + 256 * i];
#pragma unroll
    for (int r = 0; r < 2; ++r) {
        int row = r0 + r;
        int b = row >> 6;
        Z[r * 768 + j]       = nf[(size_t)row * DD + j];
        Z[r * 768 + 512 + j] = tgt[(size_t)b * DD + j];
    }
    float S0 = Svec[r0], S1 = Svec[r0 + 1];
    __syncthreads();

    // L0: 768 -> 256
    float a0 = S0 * bf0[j], a1 = S1 * bf0[j];
#pragma unroll 8
    for (int k = 0; k < 768; ++k) {
        float w = Wf0[k * 256 + j];
        a0 += A[k] * w;
        a1 += A[768 + k] * w;
    }
    H1[j] = a0; H1[256 + j] = a1;
    __syncthreads();

    // L1: 256 -> 256
    a0 = S0 * bf1[j]; a1 = S1 * bf1[j];
#pragma unroll 8
    for (int k = 0; k < 256; ++k) {
        float w = Wf1[k * 256 + j];
        a0 += H1[k] * w;
        a1 += H1[256 + k] * w;
    }
    H2[j] = a0; H2[256 + j] = a1;
    __syncthreads();

    // L2: 256 -> 256 (pre-LN retrieved), keep in registers
    a0 = S0 * bf2[j]; a1 = S1 * bf2[j];
#pragma unroll 8
    for (int k = 0; k < 256; ++k) {
        float w = Wf2[k * 256 + j];
        a0 += H2[k] * w;
        a1 += H2[256 + k] * w;
    }

    // LayerNorm per row over 256 cols; write into Z middle slot
    float g = gam[j], be = bet[j];
#pragma unroll
    for (int r = 0; r < 2; ++r) {
        float v = (r == 0) ? a0 : a1;
        float s1 = v, s2 = v * v;
#pragma unroll
        for (int off = 32; off; off >>= 1) {
            s1 += __shfl_down(s1, off, 64);
            s2 += __shfl_down(s2, off, 64);
        }
        if ((j & 63) == 0) { red1[j >> 6] = s1; red2[j >> 6] = s2; }
        __syncthreads();
        float sum = red1[0] + red1[1] + red1[2] + red1[3];
        float sq  = red2[0] + red2[1] + red2[2] + red2[3];
        float mu  = sum * (1.f / 256.f);
        float var = sq * (1.f / 256.f) - mu * mu;
        float inv = rsqrtf(var + 1e-5f);
        Z[r * 768 + 256 + j] = (v - mu) * inv * g + be;
        __syncthreads();
    }

    // L3: 768 -> 256
    a0 = bi0[j]; a1 = bi0[j];
#pragma unroll 8
    for (int k = 0; k < 768; ++k) {
        float w = Wi0[k * 256 + j];
        a0 += Z[k] * w;
        a1 += Z[768 + k] * w;
    }
    H1[j] = a0; H1[256 + j] = a1;
    __syncthreads();

    // L4: 256 -> 256
    a0 = bi1[j]; a1 = bi1[j];
#pragma unroll 8
    for (int k = 0; k < 256; ++k) {
        float w = Wi1[k * 256 + j];
        a0 += H1[k] * w;
        a1 += H1[256 + k] * w;
    }
    H2[j] = a0; H2[256 + j] = a1;
    __syncthreads();

    // L5: 256 -> 256 -> out
    a0 = bi2[j]; a1 = bi2[j];
#pragma unroll 8
    for (int k = 0; k < 256; ++k) {
        float w = Wi2[k * 256 + j];
        a0 += H2[k] * w;
        a1 += H2[256 + k] * w;
    }
    outp[(size_t)r0 * 256 + j]       = a0;
    outp[(size_t)(r0 + 1) * 256 + j] = a1;
}

extern "C" void kernel_launch(void* const* d_in, const int* in_sizes, int n_in,
                              void* d_out, int out_size, void* d_ws, size_t ws_size,
                              hipStream_t stream) {
    const float* nf  = (const float*)d_in[0];   // (B,N,D)
    const float* ef  = (const float*)d_in[1];   // (B,E,D)
    const float* tgt = (const float*)d_in[2];   // (B,D)
    const int*   ei  = (const int*)d_in[3];     // (B,2,E)
    const float* Wf0 = (const float*)d_in[4];
    const float* bf0 = (const float*)d_in[5];
    const float* Wf1 = (const float*)d_in[6];
    const float* bf1 = (const float*)d_in[7];
    const float* Wf2 = (const float*)d_in[8];
    const float* bf2 = (const float*)d_in[9];
    const float* gam = (const float*)d_in[10];
    const float* bet = (const float*)d_in[11];
    const float* Wi0 = (const float*)d_in[12];
    const float* bi0 = (const float*)d_in[13];
    const float* Wi1 = (const float*)d_in[14];
    const float* bi1 = (const float*)d_in[15];
    const float* Wi2 = (const float*)d_in[16];
    const float* bi2 = (const float*)d_in[17];
    float* out = (float*)d_out;

    float* dotv = (float*)d_ws;        // 512
    float* Svec = dotv + 512;          // 512
    float* conc = Svec + 512;          // 512*768

    k_dot<<<BB * NN, 64, 0, stream>>>(nf, tgt, dotv);
    k_edge<<<BB * NN, 256, 0, stream>>>(nf, ef, ei, dotv, conc, Svec);
    k_mlp<<<(BB * NN) / 2, 256, 0, stream>>>(conc, Svec, nf, tgt,
                                             Wf0, bf0, Wf1, bf1, Wf2, bf2,
                                             gam, bet, Wi0, bi0, Wi1, bi1, Wi2, bi2,
                                             out);
}

// Round 2
// 151.780 us; speedup vs baseline: 1.4042x; 1.4042x over previous
//
#include <hip/hip_runtime.h>

// Shapes (fixed by the problem)
#define BB 8
#define NN 64
#define DD 256
#define PP 256
#define NE 63      // N-1 edges per node
#define EE 4032    // N*(N-1) edges per batch

// dot[b*64+j] = node_features[b,j,:] . target[b,:]
__global__ __launch_bounds__(64) void k_dot(const float* __restrict__ nf,
                                            const float* __restrict__ tgt,
                                            float* __restrict__ dotv) {
    int row = blockIdx.x;          // b*NN + j
    int b = row >> 6;
    int lane = threadIdx.x;        // 0..63
    const float4* x4 = (const float4*)(nf + (size_t)row * DD);
    const float4* t4 = (const float4*)(tgt + (size_t)b * DD);
    float4 a = x4[lane];
    float4 c = t4[lane];
    float acc = a.x * c.x + a.y * c.y + a.z * c.z + a.w * c.w;
#pragma unroll
    for (int off = 32; off; off >>= 1) acc += __shfl_down(acc, off, 64);
    if (lane == 0) dotv[row] = acc;
}

// Per (b,n): s_e = dot[b, dst_e];  S = sum s_e
// conc[bn] = [ sum_e s_e*NF[src_e] | sum_e s_e*EF[e] | sum_e s_e*NF[dst_e] ]
// 512 threads: t = feature (0..255), h = e-range half (0..1)
__global__ __launch_bounds__(512) void k_edge(const float* __restrict__ nf,
                                              const float* __restrict__ ef,
                                              const int* __restrict__ eidx,
                                              const float* __restrict__ dotv,
                                              float* __restrict__ conc,
                                              float* __restrict__ Svec) {
    __shared__ float s_sh[NE];
    __shared__ int src_sh[NE];
    __shared__ int dst_sh[NE];
    __shared__ float Pat[2][256], Pus[2][256], Pud[2][256];
    int bn = blockIdx.x;           // b*NN + n
    int b = bn >> 6, n = bn & 63;
    int tid = threadIdx.x;
    int t = tid & 255;
    int h = tid >> 8;              // 0 or 1
    if (tid < NE) {
        const int* srcp = eidx + (size_t)b * 2 * EE + n * NE;
        int si = srcp[tid];
        int di = srcp[EE + tid];
        src_sh[tid] = si;
        dst_sh[tid] = di;
        s_sh[tid] = dotv[(b << 6) + di];
    }
    __syncthreads();
    const float* efp = ef + ((size_t)b * EE + (size_t)n * NE) * DD + t;
    const float* nfb = nf + ((size_t)(b << 6)) * DD + t;
    float at = 0.f, aus = 0.f, aud = 0.f;
    int e0 = h ? 32 : 0;
    int e1 = h ? 63 : 32;
#pragma unroll 8
    for (int e = e0; e < e1; ++e) {
        float sv = s_sh[e];
        at  += sv * efp[(size_t)e * DD];
        aus += sv * nfb[(size_t)src_sh[e] * DD];
        aud += sv * nfb[(size_t)dst_sh[e] * DD];
    }
    Pat[h][t] = at; Pus[h][t] = aus; Pud[h][t] = aud;
    __syncthreads();
    if (h == 0) {
        float* o = conc + (size_t)bn * 768;
        o[t]       = Pus[0][t] + Pus[1][t];
        o[256 + t] = Pat[0][t] + Pat[1][t];
        o[512 + t] = Pud[0][t] + Pud[1][t];
        if (t == 0) {
            float S = 0.f;
            for (int e = 0; e < NE; ++e) S += s_sh[e];
            Svec[bn] = S;
        }
    }
}

// 512 rows; block handles 4 rows with 1024 threads.
// thread: j = tid&255 (output column), h = tid>>8 (k-quarter AND row index for combine).
// Each thread keeps 4 accumulators (one per row) over its k-quarter, LDS-reduces.
__global__ __launch_bounds__(1024) void k_mlp(const float* __restrict__ conc,
                                              const float* __restrict__ Svec,
                                              const float* __restrict__ nf,
                                              const float* __restrict__ tgt,
                                              const float* __restrict__ Wf0, const float* __restrict__ bf0,
                                              const float* __restrict__ Wf1, const float* __restrict__ bf1,
                                              const float* __restrict__ Wf2, const float* __restrict__ bf2,
                                              const float* __restrict__ gam, const float* __restrict__ bet,
                                              const float* __restrict__ Wi0, const float* __restrict__ bi0,
                                              const float* __restrict__ Wi1, const float* __restrict__ bi1,
                                              const float* __restrict__ Wi2, const float* __restrict__ bi2,
                                              float* __restrict__ outp) {
    __shared__ float A[4 * 768];     // conc rows
    __shared__ float Z[4 * 768];     // [nf | retrieved | tgt] rows
    __shared__ float P[4][4 * 256];  // [h][r*256+j] partials
    __shared__ float H[4 * 256];     // activation rows
    __shared__ float red1[16], red2[16];
    int r0 = blockIdx.x * 4;
    int tid = threadIdx.x;
    int j = tid & 255;
    int h = tid >> 8;                // 0..3

    for (int i = tid; i < 4 * 768; i += 1024) A[i] = conc[(size_t)r0 * 768 + i];
    {
        int row = r0 + h;
        Z[h * 768 + j]       = nf[(size_t)row * DD + j];
        Z[h * 768 + 512 + j] = tgt[(size_t)(row >> 6) * DD + j];
    }
    float Sv[4];
#pragma unroll
    for (int r = 0; r < 4; ++r) Sv[r] = Svec[r0 + r];
    __syncthreads();

    // Layer: X (4 rows, stride xs), K inputs -> v (this thread's value for row h, col j).
    // If store, writes OUT[h*256+j] and syncs; caller may alias OUT with X.
    auto layer = [&](const float* X, int xs, int K, const float* __restrict__ W,
                     const float* __restrict__ bias, bool scaleS,
                     float* OUT, bool store) -> float {
        int kpart = K >> 2;
        const float* Wp = W + (size_t)h * kpart * 256 + j;
        const float* Xp = X + h * kpart;
        float a0 = 0.f, a1 = 0.f, a2 = 0.f, a3 = 0.f;
#pragma unroll 16
        for (int k = 0; k < kpart; ++k) {
            float w = Wp[(size_t)k * 256];
            a0 += Xp[k] * w;
            a1 += Xp[xs + k] * w;
            a2 += Xp[2 * xs + k] * w;
            a3 += Xp[3 * xs + k] * w;
        }
        float* Pp = P[h];
        Pp[j] = a0; Pp[256 + j] = a1; Pp[512 + j] = a2; Pp[768 + j] = a3;
        __syncthreads();
        int rj = h * 256 + j;
        float v = P[0][rj] + P[1][rj] + P[2][rj] + P[3][rj];
        v += (scaleS ? Sv[h] : 1.f) * bias[j];
        if (store) {
            OUT[rj] = v;
            __syncthreads();
        }
        return v;
    };

    layer(A, 768, 768, Wf0, bf0, true, H, true);
    layer(H, 256, 256, Wf1, bf1, true, H, true);
    float v = layer(H, 256, 256, Wf2, bf2, true, nullptr, false);

    // LayerNorm across j for each row h (4 waves per row)
    {
        float s1 = v, s2 = v * v;
#pragma unroll
        for (int off = 32; off; off >>= 1) {
            s1 += __shfl_down(s1, off, 64);
            s2 += __shfl_down(s2, off, 64);
        }
        int wv = (tid >> 6) & 3;
        if ((tid & 63) == 0) { red1[h * 4 + wv] = s1; red2[h * 4 + wv] = s2; }
        __syncthreads();
        float sum = red1[h * 4] + red1[h * 4 + 1] + red1[h * 4 + 2] + red1[h * 4 + 3];
        float sq  = red2[h * 4] + red2[h * 4 + 1] + red2[h * 4 + 2] + red2[h * 4 + 3];
        float mu  = sum * (1.f / 256.f);
        float var = sq * (1.f / 256.f) - mu * mu;
        float inv = rsqrtf(var + 1e-5f);
        Z[h * 768 + 256 + j] = (v - mu) * inv * gam[j] + bet[j];
        __syncthreads();
    }

    layer(Z, 768, 768, Wi0, bi0, false, H, true);
    layer(H, 256, 256, Wi1, bi1, false, H, true);
    float o = layer(H, 256, 256, Wi2, bi2, false, nullptr, false);
    outp[(size_t)(r0 + h) * 256 + j] = o;
}

extern "C" void kernel_launch(void* const* d_in, const int* in_sizes, int n_in,
                              void* d_out, int out_size, void* d_ws, size_t ws_size,
                              hipStream_t stream) {
    const float* nf  = (const float*)d_in[0];   // (B,N,D)
    const float* ef  = (const float*)d_in[1];   // (B,E,D)
    const float* tgt = (const float*)d_in[2];   // (B,D)
    const int*   ei  = (const int*)d_in[3];     // (B,2,E)
    const float* Wf0 = (const float*)d_in[4];
    const float* bf0 = (const float*)d_in[5];
    const float* Wf1 = (const float*)d_in[6];
    const float* bf1 = (const float*)d_in[7];
    const float* Wf2 = (const float*)d_in[8];
    const float* bf2 = (const float*)d_in[9];
    const float* gam = (const float*)d_in[10];
    const float* bet = (const float*)d_in[11];
    const float* Wi0 = (const float*)d_in[12];
    const float* bi0 = (const float*)d_in[13];
    const float* Wi1 = (const float*)d_in[14];
    const float* bi1 = (const float*)d_in[15];
    const float* Wi2 = (const float*)d_in[16];
    const float* bi2 = (const float*)d_in[17];
    float* out = (float*)d_out;

    float* dotv = (float*)d_ws;        // 512
    float* Svec = dotv + 512;          // 512
    float* conc = Svec + 512;          // 512*768

    k_dot<<<BB * NN, 64, 0, stream>>>(nf, tgt, dotv);
    k_edge<<<BB * NN, 512, 0, stream>>>(nf, ef, ei, dotv, conc, Svec);
    k_mlp<<<(BB * NN) / 4, 1024, 0, stream>>>(conc, Svec, nf, tgt,
                                              Wf0, bf0, Wf1, bf1, Wf2, bf2,
                                              gam, bet, Wi0, bi0, Wi1, bi1, Wi2, bi2,
                                              out);
}

// Round 3
// 144.725 us; speedup vs baseline: 1.4726x; 1.0487x over previous
//
#include <hip/hip_runtime.h>

// Shapes (fixed by the problem)
#define BB 8
#define NN 64
#define DD 256
#define PP 256
#define NE 63      // N-1 edges per node
#define EE 4032    // N*(N-1) edges per batch

// Fused: per (b,n) block computes s_e = nf[b,dst_e].tgt[b], S = sum s_e,
// conc[bn] = [ sum_e s_e*NF[src_e] | sum_e s_e*EF[e] | sum_e s_e*NF[dst_e] ]
// 512 threads: lane = tid&63 (float4 column group), h = tid>>6 (e-part of 8).
__global__ __launch_bounds__(512) void k_edge(const float* __restrict__ nf,
                                              const float* __restrict__ ef,
                                              const int* __restrict__ eidx,
                                              float* __restrict__ conc,
                                              float* __restrict__ Svec,
                                              const float* __restrict__ tgt) {
    __shared__ float s_sh[NE];
    __shared__ int src_sh[NE];
    __shared__ int dst_sh[NE];
    __shared__ float Psh[8 * 768];
    int bn = blockIdx.x;           // b*NN + n
    int b = bn >> 6, n = bn & 63;
    int tid = threadIdx.x;
    int lane = tid & 63;
    int h = tid >> 6;              // 0..7

    if (tid < NE) {
        const int* srcp = eidx + (size_t)b * 2 * EE + n * NE;
        src_sh[tid] = srcp[tid];
        dst_sh[tid] = srcp[EE + tid];
    }
    __syncthreads();

    const float4* nf4  = (const float4*)nf;   // [(b*64+j)*64 + lane]
    const float4* tgt4 = (const float4*)(tgt + (size_t)b * DD);
    float4 c4 = tgt4[lane];

    // Phase A: dots. Wave h handles e in [h*8, min(63,h*8+8))
    int eA0 = h * 8, eA1 = min(NE, h * 8 + 8);
    for (int e = eA0; e < eA1; ++e) {
        int d = dst_sh[e];
        float4 a4 = nf4[(size_t)((b << 6) + d) * 64 + lane];
        float p = a4.x * c4.x + a4.y * c4.y + a4.z * c4.z + a4.w * c4.w;
#pragma unroll
        for (int off = 32; off; off >>= 1) p += __shfl_down(p, off, 64);
        if (lane == 0) s_sh[e] = p;
    }
    __syncthreads();

    if (tid < 64) {
        float v = (tid < NE) ? s_sh[tid] : 0.f;
#pragma unroll
        for (int off = 32; off; off >>= 1) v += __shfl_down(v, off, 64);
        if (tid == 0) Svec[bn] = v;
    }

    // Phase B: weighted float4 sums over this wave's e-range
    const float4* ef4 = (const float4*)ef;    // [(b*EE + n*NE + e)*64 + lane]
    size_t efbase = ((size_t)b * EE + (size_t)n * NE) * 64 + lane;
    size_t nfbase = (size_t)(b << 6) * 64 + lane;
    float4 at = {0,0,0,0}, aus = {0,0,0,0}, aud = {0,0,0,0};
#pragma unroll 4
    for (int e = eA0; e < eA1; ++e) {
        float sv = s_sh[e];
        float4 fe = ef4[efbase + (size_t)e * 64];
        float4 fs = nf4[nfbase + (size_t)src_sh[e] * 64];
        float4 fd = nf4[nfbase + (size_t)dst_sh[e] * 64];
        at.x += sv * fe.x; at.y += sv * fe.y; at.z += sv * fe.z; at.w += sv * fe.w;
        aus.x += sv * fs.x; aus.y += sv * fs.y; aus.z += sv * fs.z; aus.w += sv * fs.w;
        aud.x += sv * fd.x; aud.y += sv * fd.y; aud.z += sv * fd.z; aud.w += sv * fd.w;
    }
    // Psh layout: [h][stream(0=us,1=at,2=ud)][256]
    float4* Pf4 = (float4*)Psh;
    Pf4[(size_t)(h * 3 + 0) * 64 + lane] = aus;
    Pf4[(size_t)(h * 3 + 1) * 64 + lane] = at;
    Pf4[(size_t)(h * 3 + 2) * 64 + lane] = aud;
    __syncthreads();

    float* o = conc + (size_t)bn * 768;
    for (int i = tid; i < 768; i += 512) {
        float s = 0.f;
#pragma unroll
        for (int hh = 0; hh < 8; ++hh) s += Psh[hh * 768 + i];
        o[i] = s;
    }
}

// 512 rows; block handles 4 rows with 1024 threads.
// Inner loops: jg = tid&63 (4 output cols), h = tid>>6 (16 k-parts).
// Each thread: 4 rows x 4 cols accumulators; weights via float4 (1KB/wave),
// activations via one ds_read_b128 broadcast (transposed X_T[k][4rows]).
// Combine/LN/store: col = tid&255, r2 = tid>>8.
__global__ __launch_bounds__(1024) void k_mlp(const float* __restrict__ conc,
                                              const float* __restrict__ Svec,
                                              const float* __restrict__ nf,
                                              const float* __restrict__ tgt,
                                              const float* __restrict__ Wf0, const float* __restrict__ bf0,
                                              const float* __restrict__ Wf1, const float* __restrict__ bf1,
                                              const float* __restrict__ Wf2, const float* __restrict__ bf2,
                                              const float* __restrict__ gam, const float* __restrict__ bet,
                                              const float* __restrict__ Wi0, const float* __restrict__ bi0,
                                              const float* __restrict__ Wi1, const float* __restrict__ bi1,
                                              const float* __restrict__ Wi2, const float* __restrict__ bi2,
                                              float* __restrict__ outp) {
    __shared__ float At[768 * 4];    // conc, transposed [k][r]
    __shared__ float Zt[768 * 4];    // [nf | retrieved | tgt], transposed
    __shared__ float P[16 * 4 * 256];// [h][r][col]
    __shared__ float Ht[256 * 4];    // activations, transposed [k][r]
    __shared__ float red1[16], red2[16];
    int r0 = blockIdx.x * 4;
    int tid = threadIdx.x;
    int jg = tid & 63;
    int h = tid >> 6;                // 0..15 (wave index)
    int col = tid & 255;
    int r2 = tid >> 8;               // 0..3

    // Stage inputs (transposed into LDS)
    {
        const float* cp = conc + (size_t)(r0 + r2) * 768;
#pragma unroll
        for (int q = 0; q < 3; ++q) {
            int k = col + q * 256;
            At[k * 4 + r2] = cp[k];
        }
        Zt[col * 4 + r2]         = nf[(size_t)(r0 + r2) * DD + col];
        Zt[(512 + col) * 4 + r2] = tgt[(size_t)((r0 + r2) >> 6) * DD + col];
    }
    float Sv = Svec[r0 + r2];
    __syncthreads();

    // One layer: X_T (LDS, transposed), K inputs -> per-thread value v for (r2,col).
    // If store, write OUT_T[col][r2] (may alias X_T) and sync.
    auto layer = [&](const float* Xt, int K, const float* __restrict__ W,
                     const float* __restrict__ bias, bool scaleS,
                     float* OUTt, bool store) -> float {
        int kpart = K >> 4;
        const float4* Wp = (const float4*)(W + (size_t)(h * kpart) * 256) + jg;
        const float4* Xp = (const float4*)Xt + h * kpart;
        float4 a0 = {0,0,0,0}, a1 = {0,0,0,0}, a2 = {0,0,0,0}, a3 = {0,0,0,0};
#pragma unroll 8
        for (int k = 0; k < kpart; ++k) {
            float4 w = Wp[(size_t)k * 64];
            float4 x = Xp[k];
            a0.x += x.x * w.x; a0.y += x.x * w.y; a0.z += x.x * w.z; a0.w += x.x * w.w;
            a1.x += x.y * w.x; a1.y += x.y * w.y; a1.z += x.y * w.z; a1.w += x.y * w.w;
            a2.x += x.z * w.x; a2.y += x.z * w.y; a2.z += x.z * w.z; a2.w += x.z * w.w;
            a3.x += x.w * w.x; a3.y += x.w * w.y; a3.z += x.w * w.z; a3.w += x.w * w.w;
        }
        float4* Pf4 = (float4*)P;
        Pf4[(size_t)(h * 4 + 0) * 64 + jg] = a0;
        Pf4[(size_t)(h * 4 + 1) * 64 + jg] = a1;
        Pf4[(size_t)(h * 4 + 2) * 64 + jg] = a2;
        Pf4[(size_t)(h * 4 + 3) * 64 + jg] = a3;
        __syncthreads();
        float v = 0.f;
#pragma unroll
        for (int hh = 0; hh < 16; ++hh) v += P[(hh * 4 + r2) * 256 + col];
        v += (scaleS ? Sv : 1.f) * bias[col];
        if (store) {
            OUTt[col * 4 + r2] = v;
        }
        __syncthreads();   // P reusable / OUT visible
        return v;
    };

    layer(At, 768, Wf0, bf0, true, Ht, true);
    layer(Ht, 256, Wf1, bf1, true, Ht, true);
    float v = layer(Ht, 256, Wf2, bf2, true, nullptr, false);

    // LayerNorm across col for each row r2 (4 waves per row)
    {
        float s1 = v, s2 = v * v;
#pragma unroll
        for (int off = 32; off; off >>= 1) {
            s1 += __shfl_down(s1, off, 64);
            s2 += __shfl_down(s2, off, 64);
        }
        int wv = (tid >> 6) & 3;
        if ((tid & 63) == 0) { red1[r2 * 4 + wv] = s1; red2[r2 * 4 + wv] = s2; }
        __syncthreads();
        float sum = red1[r2 * 4] + red1[r2 * 4 + 1] + red1[r2 * 4 + 2] + red1[r2 * 4 + 3];
        float sq  = red2[r2 * 4] + red2[r2 * 4 + 1] + red2[r2 * 4 + 2] + red2[r2 * 4 + 3];
        float mu  = sum * (1.f / 256.f);
        float var = sq * (1.f / 256.f) - mu * mu;
        float inv = rsqrtf(var + 1e-5f);
        Zt[(256 + col) * 4 + r2] = (v - mu) * inv * gam[col] + bet[col];
        __syncthreads();
    }

    layer(Zt, 768, Wi0, bi0, false, Ht, true);
    layer(Ht, 256, Wi1, bi1, false, Ht, true);
    float o = layer(Ht, 256, Wi2, bi2, false, nullptr, false);
    outp[(size_t)(r0 + r2) * 256 + col] = o;
}

extern "C" void kernel_launch(void* const* d_in, const int* in_sizes, int n_in,
                              void* d_out, int out_size, void* d_ws, size_t ws_size,
                              hipStream_t stream) {
    const float* nf  = (const float*)d_in[0];   // (B,N,D)
    const float* ef  = (const float*)d_in[1];   // (B,E,D)
    const float* tgt = (const float*)d_in[2];   // (B,D)
    const int*   ei  = (const int*)d_in[3];     // (B,2,E)
    const float* Wf0 = (const float*)d_in[4];
    const float* bf0 = (const float*)d_in[5];
    const float* Wf1 = (const float*)d_in[6];
    const float* bf1 = (const float*)d_in[7];
    const float* Wf2 = (const float*)d_in[8];
    const float* bf2 = (const float*)d_in[9];
    const float* gam = (const float*)d_in[10];
    const float* bet = (const float*)d_in[11];
    const float* Wi0 = (const float*)d_in[12];
    const float* bi0 = (const float*)d_in[13];
    const float* Wi1 = (const float*)d_in[14];
    const float* bi1 = (const float*)d_in[15];
    const float* Wi2 = (const float*)d_in[16];
    const float* bi2 = (const float*)d_in[17];
    float* out = (float*)d_out;

    float* Svec = (float*)d_ws;        // 512
    float* conc = Svec + 512;          // 512*768

    k_edge<<<BB * NN, 512, 0, stream>>>(nf, ef, ei, conc, Svec, tgt);
    k_mlp<<<(BB * NN) / 4, 1024, 0, stream>>>(conc, Svec, nf, tgt,
                                              Wf0, bf0, Wf1, bf1, Wf2, bf2,
                                              gam, bet, Wi0, bi0, Wi1, bi1, Wi2, bi2,
                                              out);
}

// Round 4
// 143.641 us; speedup vs baseline: 1.4837x; 1.0075x over previous
//
#include <hip/hip_runtime.h>

// Shapes (fixed by the problem)
#define BB 8
#define NN 64
#define DD 256
#define PP 256
#define NE 63      // N-1 edges per node
#define EE 4032    // N*(N-1) edges per batch

typedef _Float16 half4 __attribute__((ext_vector_type(4)));
typedef _Float16 half2v __attribute__((ext_vector_type(2)));

// Convert the 6 weight matrices to fp16 into workspace (once per call).
// Segment sizes: Wf0 196608, Wf1 65536, Wf2 65536, Wi0 196608, Wi1 65536, Wi2 65536.
__global__ __launch_bounds__(256) void k_wconv(const float* __restrict__ Wf0, const float* __restrict__ Wf1,
                                               const float* __restrict__ Wf2, const float* __restrict__ Wi0,
                                               const float* __restrict__ Wi1, const float* __restrict__ Wi2,
                                               _Float16* __restrict__ o) {
    int i = (blockIdx.x * 256 + threadIdx.x) * 2;   // even, < 655360
    const float* src; int off;
    if (i < 196608)      { src = Wf0; off = 0; }
    else if (i < 262144) { src = Wf1; off = 196608; }
    else if (i < 327680) { src = Wf2; off = 262144; }
    else if (i < 524288) { src = Wi0; off = 327680; }
    else if (i < 589824) { src = Wi1; off = 524288; }
    else                 { src = Wi2; off = 589824; }
    float2 v = *(const float2*)(src + (i - off));
    half2v h; h.x = (_Float16)v.x; h.y = (_Float16)v.y;
    *(half2v*)(o + i) = h;
}

// dot[b*64+j] = node_features[b,j,:] . target[b,:]
__global__ __launch_bounds__(64) void k_dot(const float* __restrict__ nf,
                                            const float* __restrict__ tgt,
                                            float* __restrict__ dotv) {
    int row = blockIdx.x;          // b*NN + j
    int b = row >> 6;
    int lane = threadIdx.x;        // 0..63
    const float4* x4 = (const float4*)(nf + (size_t)row * DD);
    const float4* t4 = (const float4*)(tgt + (size_t)b * DD);
    float4 a = x4[lane];
    float4 c = t4[lane];
    float acc = a.x * c.x + a.y * c.y + a.z * c.z + a.w * c.w;
#pragma unroll
    for (int off = 32; off; off >>= 1) acc += __shfl_down(acc, off, 64);
    if (lane == 0) dotv[row] = acc;
}

// Per (b,n): s_e = dotv[b,dst_e]; S = sum s_e
// conc[bn] = [ sum s_e*NF[src_e] | sum s_e*EF[e] | sum s_e*NF[dst_e] ]
// 1024 threads: lane = tid&63 (float4 col group), h = tid>>6 (16 e-parts of 4).
__global__ __launch_bounds__(1024) void k_edge(const float* __restrict__ nf,
                                               const float* __restrict__ ef,
                                               const int* __restrict__ eidx,
                                               const float* __restrict__ dotv,
                                               float* __restrict__ conc,
                                               float* __restrict__ Svec) {
    __shared__ float s_sh[64];
    __shared__ int src_sh[NE];
    __shared__ int dst_sh[NE];
    __shared__ float Psh[16 * 768];
    int bn = blockIdx.x;           // b*NN + n
    int b = bn >> 6, n = bn & 63;
    int tid = threadIdx.x;
    int lane = tid & 63;
    int h = tid >> 6;              // 0..15

    if (tid < NE) {
        const int* srcp = eidx + (size_t)b * 2 * EE + n * NE;
        int si = srcp[tid];
        int di = srcp[EE + tid];
        src_sh[tid] = si;
        dst_sh[tid] = di;
        s_sh[tid] = dotv[(b << 6) + di];
    }
    __syncthreads();

    if (tid < 64) {
        float v = (tid < NE) ? s_sh[tid] : 0.f;
#pragma unroll
        for (int off = 32; off; off >>= 1) v += __shfl_down(v, off, 64);
        if (tid == 0) Svec[bn] = v;
    }

    const float4* nf4 = (const float4*)nf;
    const float4* ef4 = (const float4*)ef;
    size_t efbase = ((size_t)b * EE + (size_t)n * NE) * 64 + lane;
    size_t nfbase = (size_t)(b << 6) * 64 + lane;
    int e0 = h * 4, e1 = min(NE, h * 4 + 4);
    float4 at = {0,0,0,0}, aus = {0,0,0,0}, aud = {0,0,0,0};
#pragma unroll 4
    for (int e = e0; e < e1; ++e) {
        float sv = s_sh[e];
        float4 fe = ef4[efbase + (size_t)e * 64];
        float4 fs = nf4[nfbase + (size_t)src_sh[e] * 64];
        float4 fd = nf4[nfbase + (size_t)dst_sh[e] * 64];
        at.x += sv * fe.x; at.y += sv * fe.y; at.z += sv * fe.z; at.w += sv * fe.w;
        aus.x += sv * fs.x; aus.y += sv * fs.y; aus.z += sv * fs.z; aus.w += sv * fs.w;
        aud.x += sv * fd.x; aud.y += sv * fd.y; aud.z += sv * fd.z; aud.w += sv * fd.w;
    }
    // Psh layout: [h][stream(0=us,1=at,2=ud)][256]
    float4* Pf4 = (float4*)Psh;
    Pf4[(size_t)(h * 3 + 0) * 64 + lane] = aus;
    Pf4[(size_t)(h * 3 + 1) * 64 + lane] = at;
    Pf4[(size_t)(h * 3 + 2) * 64 + lane] = aud;
    __syncthreads();

    if (tid < 768) {
        float s = 0.f;
#pragma unroll
        for (int hh = 0; hh < 16; ++hh) s += Psh[hh * 768 + tid];
        conc[(size_t)bn * 768 + tid] = s;
    }
}

// 512 rows; block = 4 rows, 1024 threads.
// Inner: jg = tid&63 (4 cols via half4 weight load), h = tid>>6 (16 k-parts).
// Combine/LN/store: col = tid&255, r2 = tid>>8.
__global__ __launch_bounds__(1024) void k_mlp(const float* __restrict__ conc,
                                              const float* __restrict__ Svec,
                                              const float* __restrict__ nf,
                                              const float* __restrict__ tgt,
                                              const _Float16* __restrict__ Wh,
                                              const float* __restrict__ bf0,
                                              const float* __restrict__ bf1,
                                              const float* __restrict__ bf2,
                                              const float* __restrict__ gam, const float* __restrict__ bet,
                                              const float* __restrict__ bi0,
                                              const float* __restrict__ bi1,
                                              const float* __restrict__ bi2,
                                              float* __restrict__ outp) {
    __shared__ float At[768 * 4];    // conc, transposed [k][r]
    __shared__ float Zt[768 * 4];    // [nf | retrieved | tgt], transposed
    __shared__ float P[16 * 4 * 256];// [h][r][col]
    __shared__ float Ht[256 * 4];    // activations, transposed [k][r]
    __shared__ float red1[16], red2[16];
    int r0 = blockIdx.x * 4;
    int tid = threadIdx.x;
    int jg = tid & 63;
    int h = tid >> 6;                // 0..15 (wave index)
    int col = tid & 255;
    int r2 = tid >> 8;               // 0..3

    const _Float16* Wf0h = Wh;
    const _Float16* Wf1h = Wh + 196608;
    const _Float16* Wf2h = Wh + 262144;
    const _Float16* Wi0h = Wh + 327680;
    const _Float16* Wi1h = Wh + 524288;
    const _Float16* Wi2h = Wh + 589824;

    {
        const float* cp = conc + (size_t)(r0 + r2) * 768;
#pragma unroll
        for (int q = 0; q < 3; ++q) {
            int k = col + q * 256;
            At[k * 4 + r2] = cp[k];
        }
        Zt[col * 4 + r2]         = nf[(size_t)(r0 + r2) * DD + col];
        Zt[(512 + col) * 4 + r2] = tgt[(size_t)((r0 + r2) >> 6) * DD + col];
    }
    float Sv = Svec[r0 + r2];
    __syncthreads();

    auto layer = [&](const float* Xt, int K, const _Float16* __restrict__ W,
                     const float* __restrict__ bias, bool scaleS,
                     float* OUTt, bool store) -> float {
        int kpart = K >> 4;
        const half4* Wp = (const half4*)(W + (size_t)(h * kpart) * 256) + jg;
        const float4* Xp = (const float4*)Xt + h * kpart;
        float4 a0 = {0,0,0,0}, a1 = {0,0,0,0}, a2 = {0,0,0,0}, a3 = {0,0,0,0};
#pragma unroll 8
        for (int k = 0; k < kpart; ++k) {
            half4 wh = Wp[(size_t)k * 64];
            float4 x = Xp[k];
            float wx = (float)wh.x, wy = (float)wh.y, wz = (float)wh.z, ww = (float)wh.w;
            a0.x += x.x * wx; a0.y += x.x * wy; a0.z += x.x * wz; a0.w += x.x * ww;
            a1.x += x.y * wx; a1.y += x.y * wy; a1.z += x.y * wz; a1.w += x.y * ww;
            a2.x += x.z * wx; a2.y += x.z * wy; a2.z += x.z * wz; a2.w += x.z * ww;
            a3.x += x.w * wx; a3.y += x.w * wy; a3.z += x.w * wz; a3.w += x.w * ww;
        }
        float4* Pf4 = (float4*)P;
        Pf4[(size_t)(h * 4 + 0) * 64 + jg] = a0;
        Pf4[(size_t)(h * 4 + 1) * 64 + jg] = a1;
        Pf4[(size_t)(h * 4 + 2) * 64 + jg] = a2;
        Pf4[(size_t)(h * 4 + 3) * 64 + jg] = a3;
        __syncthreads();
        float v = 0.f;
#pragma unroll
        for (int hh = 0; hh < 16; ++hh) v += P[(hh * 4 + r2) * 256 + col];
        v += (scaleS ? Sv : 1.f) * bias[col];
        if (store) {
            OUTt[col * 4 + r2] = v;
        }
        __syncthreads();
        return v;
    };

    layer(At, 768, Wf0h, bf0, true, Ht, true);
    layer(Ht, 256, Wf1h, bf1, true, Ht, true);
    float v = layer(Ht, 256, Wf2h, bf2, true, nullptr, false);

    // LayerNorm across col for each row r2 (4 waves per row)
    {
        float s1 = v, s2 = v * v;
#pragma unroll
        for (int off = 32; off; off >>= 1) {
            s1 += __shfl_down(s1, off, 64);
            s2 += __shfl_down(s2, off, 64);
        }
        int wv = (tid >> 6) & 3;
        if ((tid & 63) == 0) { red1[r2 * 4 + wv] = s1; red2[r2 * 4 + wv] = s2; }
        __syncthreads();
        float sum = red1[r2 * 4] + red1[r2 * 4 + 1] + red1[r2 * 4 + 2] + red1[r2 * 4 + 3];
        float sq  = red2[r2 * 4] + red2[r2 * 4 + 1] + red2[r2 * 4 + 2] + red2[r2 * 4 + 3];
        float mu  = sum * (1.f / 256.f);
        float var = sq * (1.f / 256.f) - mu * mu;
        float inv = rsqrtf(var + 1e-5f);
        Zt[(256 + col) * 4 + r2] = (v - mu) * inv * gam[col] + bet[col];
        __syncthreads();
    }

    layer(Zt, 768, Wi0h, bi0, false, Ht, true);
    layer(Ht, 256, Wi1h, bi1, false, Ht, true);
    float o = layer(Ht, 256, Wi2h, bi2, false, nullptr, false);
    outp[(size_t)(r0 + r2) * 256 + col] = o;
}

extern "C" void kernel_launch(void* const* d_in, const int* in_sizes, int n_in,
                              void* d_out, int out_size, void* d_ws, size_t ws_size,
                              hipStream_t stream) {
    const float* nf  = (const float*)d_in[0];   // (B,N,D)
    const float* ef  = (const float*)d_in[1];   // (B,E,D)
    const float* tgt = (const float*)d_in[2];   // (B,D)
    const int*   ei  = (const int*)d_in[3];     // (B,2,E)
    const float* Wf0 = (const float*)d_in[4];
    const float* bf0 = (const float*)d_in[5];
    const float* Wf1 = (const float*)d_in[6];
    const float* bf1 = (const float*)d_in[7];
    const float* Wf2 = (const float*)d_in[8];
    const float* bf2 = (const float*)d_in[9];
    const float* gam = (const float*)d_in[10];
    const float* bet = (const float*)d_in[11];
    const float* Wi0 = (const float*)d_in[12];
    const float* bi0 = (const float*)d_in[13];
    const float* Wi1 = (const float*)d_in[14];
    const float* bi1 = (const float*)d_in[15];
    const float* Wi2 = (const float*)d_in[16];
    const float* bi2 = (const float*)d_in[17];
    float* out = (float*)d_out;

    float* dotv = (float*)d_ws;            // 512
    float* Svec = dotv + 512;              // 512
    float* conc = Svec + 512;              // 512*768 = 393216
    _Float16* wh = (_Float16*)(conc + 512 * 768);  // 655360 halfs

    k_wconv<<<655360 / 512, 256, 0, stream>>>(Wf0, Wf1, Wf2, Wi0, Wi1, Wi2, wh);
    k_dot<<<BB * NN, 64, 0, stream>>>(nf, tgt, dotv);
    k_edge<<<BB * NN, 1024, 0, stream>>>(nf, ef, ei, dotv, conc, Svec);
    k_mlp<<<(BB * NN) / 4, 1024, 0, stream>>>(conc, Svec, nf, tgt, wh,
                                              bf0, bf1, bf2, gam, bet,
                                              bi0, bi1, bi2, out);
}